// Round 1
// baseline (994.033 us; speedup 1.0000x reference)
//
#include <hip/hip_runtime.h>

// GraphSAGE 2-layer, N=500000 nodes, E=5000000 edges.
// Key trick: mean-agg commutes with linear maps ->
//   layer2 aggregates the SCALAR s = h . W2l instead of 16-wide h.
// h is never materialized; recomputed per-node in the final pass.

static constexpr int BLOCK = 256;

// ---------------- edge scatter, layer 1: agg1 += x[src], deg += 1 -----------
__global__ __launch_bounds__(256) void k_scatter1(
    const int* __restrict__ src, const int* __restrict__ dst,
    const float* __restrict__ x,
    float* __restrict__ agg1, float* __restrict__ deg, int E)
{
    int stride = gridDim.x * blockDim.x;
    for (int e = blockIdx.x * blockDim.x + threadIdx.x; e < E; e += stride) {
        int s = src[e];
        int d = dst[e];
        float2 xv = *reinterpret_cast<const float2*>(x + 2 * (size_t)s);
        unsafeAtomicAdd(&agg1[2 * (size_t)d + 0], xv.x);
        unsafeAtomicAdd(&agg1[2 * (size_t)d + 1], xv.y);
        unsafeAtomicAdd(&deg[d], 1.0f);
    }
}

// ---------------- node pass 1: s[i] = relu(h_i) . W2l ----------------------
__global__ __launch_bounds__(256) void k_node1(
    const float* __restrict__ x,
    const float* __restrict__ agg1, const float* __restrict__ deg,
    const float* __restrict__ W1l, const float* __restrict__ b1,
    const float* __restrict__ W1r, const float* __restrict__ W2l,
    float* __restrict__ sval, int N)
{
    int i = blockIdx.x * blockDim.x + threadIdx.x;
    if (i >= N) return;
    float inv = 1.0f / fmaxf(deg[i], 1.0f);
    float2 a = *reinterpret_cast<const float2*>(agg1 + 2 * (size_t)i);
    float m0 = a.x * inv, m1 = a.y * inv;
    float2 xv = *reinterpret_cast<const float2*>(x + 2 * (size_t)i);
    float s = 0.0f;
#pragma unroll
    for (int o = 0; o < 16; ++o) {
        float h = m0 * W1l[2 * o] + m1 * W1l[2 * o + 1] + b1[o]
                + xv.x * W1r[2 * o] + xv.y * W1r[2 * o + 1];
        h = fmaxf(h, 0.0f);
        s += h * W2l[o];
    }
    sval[i] = s;
}

// ---------------- edge scatter, layer 2: agg_s += s[src] -------------------
__global__ __launch_bounds__(256) void k_scatter2(
    const int* __restrict__ src, const int* __restrict__ dst,
    const float* __restrict__ sval,
    float* __restrict__ agg_s, int E)
{
    int stride = gridDim.x * blockDim.x;
    for (int e = blockIdx.x * blockDim.x + threadIdx.x; e < E; e += stride) {
        int s = src[e];
        int d = dst[e];
        unsafeAtomicAdd(&agg_s[d], sval[s]);
    }
}

// ---------------- node pass 2: out = sigmoid(agg_s/deg + b2 + h . W2r) -----
__global__ __launch_bounds__(256) void k_node2(
    const float* __restrict__ x,
    const float* __restrict__ agg1, const float* __restrict__ deg,
    const float* __restrict__ agg_s,
    const float* __restrict__ W1l, const float* __restrict__ b1,
    const float* __restrict__ W1r, const float* __restrict__ W2r,
    const float* __restrict__ b2,
    float* __restrict__ out, int N)
{
    int i = blockIdx.x * blockDim.x + threadIdx.x;
    if (i >= N) return;
    float inv = 1.0f / fmaxf(deg[i], 1.0f);
    float2 a = *reinterpret_cast<const float2*>(agg1 + 2 * (size_t)i);
    float m0 = a.x * inv, m1 = a.y * inv;
    float2 xv = *reinterpret_cast<const float2*>(x + 2 * (size_t)i);
    float t = agg_s[i] * inv + b2[0];
#pragma unroll
    for (int o = 0; o < 16; ++o) {
        float h = m0 * W1l[2 * o] + m1 * W1l[2 * o + 1] + b1[o]
                + xv.x * W1r[2 * o] + xv.y * W1r[2 * o + 1];
        h = fmaxf(h, 0.0f);
        t += h * W2r[o];
    }
    out[i] = 1.0f / (1.0f + expf(-t));
}

extern "C" void kernel_launch(void* const* d_in, const int* in_sizes, int n_in,
                              void* d_out, int out_size, void* d_ws, size_t ws_size,
                              hipStream_t stream) {
    const float* x   = (const float*)d_in[0];
    const int*   ei  = (const int*)d_in[1];
    const float* W1l = (const float*)d_in[2];
    const float* b1  = (const float*)d_in[3];
    const float* W1r = (const float*)d_in[4];
    const float* W2l = (const float*)d_in[5];
    const float* b2  = (const float*)d_in[6];
    const float* W2r = (const float*)d_in[7];

    const int N = in_sizes[0] / 2;   // 500000
    const int E = in_sizes[1] / 2;   // 5000000
    const int* src = ei;
    const int* dst = ei + (size_t)E;

    // workspace layout (floats): agg1[2N] | deg[N] | agg_s[N] | s[N]
    float* agg1  = (float*)d_ws;
    float* deg   = agg1 + 2 * (size_t)N;
    float* agg_s = deg + (size_t)N;
    float* sval  = agg_s + (size_t)N;
    float* out   = (float*)d_out;

    // zero the accumulators (agg1, deg, agg_s are contiguous: 4N floats)
    hipMemsetAsync(d_ws, 0, 4 * (size_t)N * sizeof(float), stream);

    const int eblocks = 2048;                    // grid-stride over edges
    const int nblocks = (N + BLOCK - 1) / BLOCK; // exact over nodes

    k_scatter1<<<eblocks, BLOCK, 0, stream>>>(src, dst, x, agg1, deg, E);
    k_node1<<<nblocks, BLOCK, 0, stream>>>(x, agg1, deg, W1l, b1, W1r, W2l, sval, N);
    k_scatter2<<<eblocks, BLOCK, 0, stream>>>(src, dst, sval, agg_s, E);
    k_node2<<<nblocks, BLOCK, 0, stream>>>(x, agg1, deg, agg_s, W1l, b1, W1r, W2r, b2, out, N);
}

// Round 2
// 498.350 us; speedup vs baseline: 1.9946x; 1.9946x over previous
//
#include <hip/hip_runtime.h>

// GraphSAGE 2-layer, N=500000, E=5000000.
// Strategy:
//  - mean-agg commutes with linear layers -> layer2 aggregates scalar s = relu(h).W2l
//  - XCD-private accumulator copies + L2-local (no sc1) atomics via inline asm:
//    avoids memory-side write-through RMW (round-1: 468MB writes, 20G atomics/s cap)
//  - layer-1 (x0,x1,deg) packed into ONE u64 fixed-point atomic per edge:
//    fields deg[63:56] | q0[55:28] | q1[27:0], scale 2^18, bias +8.0 per add.
//    deg<=~35 -> field sums < 2^28, no cross-field carries; quant err ~4e-6.

static constexpr int BLOCK = 256;
static constexpr int NXCD = 8;
static constexpr float SCALE = 262144.0f;        // 2^18
static constexpr float INV_SCALE = 1.0f / 262144.0f;

__device__ __forceinline__ unsigned xcd_id() {
    unsigned v;
    asm("s_getreg_b32 %0, hwreg(HW_REG_XCC_ID)" : "=s"(v));
    return v & 7u;
}

// L2-local atomics: no sc0 (no return), no sc1 (stays in this XCD's L2, cached).
__device__ __forceinline__ void atom_add_u64_l2(unsigned long long* p, unsigned long long v) {
    asm volatile("global_atomic_add_x2 %0, %1, off" :: "v"(p), "v"(v) : "memory");
}
__device__ __forceinline__ void atom_add_f32_l2(float* p, float v) {
    asm volatile("global_atomic_add_f32 %0, %1, off" :: "v"(p), "v"(v) : "memory");
}

__device__ __forceinline__ unsigned long long pack_edge(float x0, float x1) {
    int q0 = __float2int_rn((x0 + 8.0f) * SCALE);   // in [~0.65M, ~3.5M] < 2^22
    int q1 = __float2int_rn((x1 + 8.0f) * SCALE);
    return (1ULL << 56) | ((unsigned long long)(unsigned)q0 << 28)
                        | (unsigned long long)(unsigned)q1;
}

// ---------------- edge scatter, layer 1: one u64 atomic per edge ------------
__global__ __launch_bounds__(256) void k_sc1(
    const int* __restrict__ src, const int* __restrict__ dst,
    const float* __restrict__ x,
    unsigned long long* __restrict__ acc, int E, int N)
{
    unsigned long long* mine = acc + (size_t)xcd_id() * (size_t)N;
    int stride = gridDim.x * blockDim.x;
    for (int i = blockIdx.x * blockDim.x + threadIdx.x; 4 * i < E; i += stride) {
        int e0 = 4 * i;
        if (e0 + 3 < E) {
            int4 s4 = *reinterpret_cast<const int4*>(src + e0);
            int4 d4 = *reinterpret_cast<const int4*>(dst + e0);
            float2 a = *reinterpret_cast<const float2*>(x + 2 * (size_t)s4.x);
            float2 b = *reinterpret_cast<const float2*>(x + 2 * (size_t)s4.y);
            float2 c = *reinterpret_cast<const float2*>(x + 2 * (size_t)s4.z);
            float2 d = *reinterpret_cast<const float2*>(x + 2 * (size_t)s4.w);
            atom_add_u64_l2(mine + d4.x, pack_edge(a.x, a.y));
            atom_add_u64_l2(mine + d4.y, pack_edge(b.x, b.y));
            atom_add_u64_l2(mine + d4.z, pack_edge(c.x, c.y));
            atom_add_u64_l2(mine + d4.w, pack_edge(d.x, d.y));
        } else {
            for (int e = e0; e < E; ++e) {
                int s = src[e], d = dst[e];
                float2 xv = *reinterpret_cast<const float2*>(x + 2 * (size_t)s);
                atom_add_u64_l2(mine + d, pack_edge(xv.x, xv.y));
            }
        }
    }
}

// ---- merge copies + node pass 1: sval = relu(h).W2l, t0 = b2 + relu(h).W2r --
__global__ __launch_bounds__(256) void k_merge1(
    const unsigned long long* __restrict__ acc,
    const float* __restrict__ x,
    const float* __restrict__ W1l, const float* __restrict__ b1,
    const float* __restrict__ W1r, const float* __restrict__ W2l,
    const float* __restrict__ W2r, const float* __restrict__ b2,
    float* __restrict__ sval, float* __restrict__ t0a, float* __restrict__ inva,
    int N)
{
    int i = blockIdx.x * blockDim.x + threadIdx.x;
    if (i >= N) return;
    unsigned long long t = 0;
#pragma unroll
    for (int k = 0; k < NXCD; ++k) t += acc[(size_t)k * N + i];
    int deg = (int)(t >> 56);
    long long q0 = (long long)((t >> 28) & 0xFFFFFFFULL);
    long long q1 = (long long)(t & 0xFFFFFFFULL);
    long long bias = (long long)deg * (8LL * 262144LL);
    float inv = 1.0f / (float)max(deg, 1);
    float m0 = (float)(q0 - bias) * INV_SCALE * inv;
    float m1 = (float)(q1 - bias) * INV_SCALE * inv;
    float2 xv = *reinterpret_cast<const float2*>(x + 2 * (size_t)i);
    float s = 0.0f, t0 = b2[0];
#pragma unroll
    for (int o = 0; o < 16; ++o) {
        float h = m0 * W1l[2 * o] + m1 * W1l[2 * o + 1] + b1[o]
                + xv.x * W1r[2 * o] + xv.y * W1r[2 * o + 1];
        h = fmaxf(h, 0.0f);
        s  += h * W2l[o];
        t0 += h * W2r[o];
    }
    sval[i] = s;
    t0a[i]  = t0;
    inva[i] = inv;
}

// ---------------- edge scatter, layer 2: one f32 atomic per edge ------------
__global__ __launch_bounds__(256) void k_sc2(
    const int* __restrict__ src, const int* __restrict__ dst,
    const float* __restrict__ sval,
    float* __restrict__ aggs, int E, int N)
{
    float* mine = aggs + (size_t)xcd_id() * (size_t)N;
    int stride = gridDim.x * blockDim.x;
    for (int i = blockIdx.x * blockDim.x + threadIdx.x; 4 * i < E; i += stride) {
        int e0 = 4 * i;
        if (e0 + 3 < E) {
            int4 s4 = *reinterpret_cast<const int4*>(src + e0);
            int4 d4 = *reinterpret_cast<const int4*>(dst + e0);
            atom_add_f32_l2(mine + d4.x, sval[s4.x]);
            atom_add_f32_l2(mine + d4.y, sval[s4.y]);
            atom_add_f32_l2(mine + d4.z, sval[s4.z]);
            atom_add_f32_l2(mine + d4.w, sval[s4.w]);
        } else {
            for (int e = e0; e < E; ++e)
                atom_add_f32_l2(mine + dst[e], sval[src[e]]);
        }
    }
}

// ---------------- merge + node pass 2: out = sigmoid(mean_s + t0) -----------
__global__ __launch_bounds__(256) void k_merge2(
    const float* __restrict__ aggs,
    const float* __restrict__ t0a, const float* __restrict__ inva,
    float* __restrict__ out, int N)
{
    int i = blockIdx.x * blockDim.x + threadIdx.x;
    if (i >= N) return;
    float ssum = 0.0f;
#pragma unroll
    for (int k = 0; k < NXCD; ++k) ssum += aggs[(size_t)k * N + i];
    float t = ssum * inva[i] + t0a[i];
    out[i] = 1.0f / (1.0f + expf(-t));
}

// =================== fallback (round-1 path, needs only 20B/node) ===========
__global__ __launch_bounds__(256) void k_scatter1_fb(
    const int* __restrict__ src, const int* __restrict__ dst,
    const float* __restrict__ x,
    float* __restrict__ agg1, float* __restrict__ deg, int E)
{
    int stride = gridDim.x * blockDim.x;
    for (int e = blockIdx.x * blockDim.x + threadIdx.x; e < E; e += stride) {
        int s = src[e], d = dst[e];
        float2 xv = *reinterpret_cast<const float2*>(x + 2 * (size_t)s);
        unsafeAtomicAdd(&agg1[2 * (size_t)d + 0], xv.x);
        unsafeAtomicAdd(&agg1[2 * (size_t)d + 1], xv.y);
        unsafeAtomicAdd(&deg[d], 1.0f);
    }
}
__global__ __launch_bounds__(256) void k_node1_fb(
    const float* __restrict__ x,
    const float* __restrict__ agg1, const float* __restrict__ deg,
    const float* __restrict__ W1l, const float* __restrict__ b1,
    const float* __restrict__ W1r, const float* __restrict__ W2l,
    float* __restrict__ sval, int N)
{
    int i = blockIdx.x * blockDim.x + threadIdx.x;
    if (i >= N) return;
    float inv = 1.0f / fmaxf(deg[i], 1.0f);
    float2 a = *reinterpret_cast<const float2*>(agg1 + 2 * (size_t)i);
    float m0 = a.x * inv, m1 = a.y * inv;
    float2 xv = *reinterpret_cast<const float2*>(x + 2 * (size_t)i);
    float s = 0.0f;
#pragma unroll
    for (int o = 0; o < 16; ++o) {
        float h = m0 * W1l[2 * o] + m1 * W1l[2 * o + 1] + b1[o]
                + xv.x * W1r[2 * o] + xv.y * W1r[2 * o + 1];
        s += fmaxf(h, 0.0f) * W2l[o];
    }
    sval[i] = s;
}
__global__ __launch_bounds__(256) void k_scatter2_fb(
    const int* __restrict__ src, const int* __restrict__ dst,
    const float* __restrict__ sval, float* __restrict__ agg_s, int E)
{
    int stride = gridDim.x * blockDim.x;
    for (int e = blockIdx.x * blockDim.x + threadIdx.x; e < E; e += stride)
        unsafeAtomicAdd(&agg_s[dst[e]], sval[src[e]]);
}
__global__ __launch_bounds__(256) void k_node2_fb(
    const float* __restrict__ x,
    const float* __restrict__ agg1, const float* __restrict__ deg,
    const float* __restrict__ agg_s,
    const float* __restrict__ W1l, const float* __restrict__ b1,
    const float* __restrict__ W1r, const float* __restrict__ W2r,
    const float* __restrict__ b2,
    float* __restrict__ out, int N)
{
    int i = blockIdx.x * blockDim.x + threadIdx.x;
    if (i >= N) return;
    float inv = 1.0f / fmaxf(deg[i], 1.0f);
    float2 a = *reinterpret_cast<const float2*>(agg1 + 2 * (size_t)i);
    float m0 = a.x * inv, m1 = a.y * inv;
    float2 xv = *reinterpret_cast<const float2*>(x + 2 * (size_t)i);
    float t = agg_s[i] * inv + b2[0];
#pragma unroll
    for (int o = 0; o < 16; ++o) {
        float h = m0 * W1l[2 * o] + m1 * W1l[2 * o + 1] + b1[o]
                + xv.x * W1r[2 * o] + xv.y * W1r[2 * o + 1];
        t += fmaxf(h, 0.0f) * W2r[o];
    }
    out[i] = 1.0f / (1.0f + expf(-t));
}

extern "C" void kernel_launch(void* const* d_in, const int* in_sizes, int n_in,
                              void* d_out, int out_size, void* d_ws, size_t ws_size,
                              hipStream_t stream) {
    const float* x   = (const float*)d_in[0];
    const int*   ei  = (const int*)d_in[1];
    const float* W1l = (const float*)d_in[2];
    const float* b1  = (const float*)d_in[3];
    const float* W1r = (const float*)d_in[4];
    const float* W2l = (const float*)d_in[5];
    const float* b2  = (const float*)d_in[6];
    const float* W2r = (const float*)d_in[7];

    const int N = in_sizes[0] / 2;   // 500000
    const int E = in_sizes[1] / 2;   // 5000000
    const int* src = ei;
    const int* dst = ei + (size_t)E;
    float* out = (float*)d_out;

    const int eblocks = 2048;
    const int nblocks = (N + BLOCK - 1) / BLOCK;

    // ws layout: acc u64[8][N] | aggs f32[8][N] | sval[N] | t0[N] | inv[N]
    size_t needed = (size_t)N * (8 * 8 + 8 * 4 + 4 + 4 + 4);
    if (ws_size >= needed) {
        unsigned long long* acc = (unsigned long long*)d_ws;
        float* aggs = (float*)(acc + (size_t)NXCD * N);
        float* sval = aggs + (size_t)NXCD * N;
        float* t0a  = sval + (size_t)N;
        float* inva = t0a + (size_t)N;

        // zero the atomic targets (acc + aggs are contiguous: 96B/node)
        hipMemsetAsync(d_ws, 0, (size_t)N * 96, stream);

        k_sc1<<<eblocks, BLOCK, 0, stream>>>(src, dst, x, acc, E, N);
        k_merge1<<<nblocks, BLOCK, 0, stream>>>(acc, x, W1l, b1, W1r, W2l, W2r, b2,
                                                sval, t0a, inva, N);
        k_sc2<<<eblocks, BLOCK, 0, stream>>>(src, dst, sval, aggs, E, N);
        k_merge2<<<nblocks, BLOCK, 0, stream>>>(aggs, t0a, inva, out, N);
    } else {
        // fallback: round-1 proven path (5N floats)
        float* agg1  = (float*)d_ws;
        float* deg   = agg1 + 2 * (size_t)N;
        float* agg_s = deg + (size_t)N;
        float* sval  = agg_s + (size_t)N;
        hipMemsetAsync(d_ws, 0, 4 * (size_t)N * sizeof(float), stream);
        k_scatter1_fb<<<eblocks, BLOCK, 0, stream>>>(src, dst, x, agg1, deg, E);
        k_node1_fb<<<nblocks, BLOCK, 0, stream>>>(x, agg1, deg, W1l, b1, W1r, W2l, sval, N);
        k_scatter2_fb<<<eblocks, BLOCK, 0, stream>>>(src, dst, sval, agg_s, E);
        k_node2_fb<<<nblocks, BLOCK, 0, stream>>>(x, agg1, deg, agg_s, W1l, b1, W1r, W2r, b2, out, N);
    }
}

// Round 3
// 123.295 us; speedup vs baseline: 8.0622x; 4.0419x over previous
//
#include <hip/hip_runtime.h>

// GraphSAGE 2-layer, N=500000, E=5000000.
// Round-3 strategy: global atomics are memory-side on gfx950 (~20G ops/s,
// 32B write-through each — measured). Eliminate them:
//   1. k_part: partition edges into buckets by dst>>10 (1024 nodes/bucket),
//      contiguous per-(block,bucket) claims -> only ~125K global atomics.
//      entry u32 = (src<<10) | (dst&1023).
//   2. k_agg1: one block per bucket, LDS integer bins (ds_atomic), fused
//      node MLP -> sval (quantized), t0, inv, deg. Exclusive ranges -> plain stores.
//   3. k_agg2: same structure for layer-2 scalar agg, fused sigmoid.
// All aggregation is fixed-point integer => bit-deterministic regardless of
// claim/scatter order. Quant err ~1e-4 << 1.8e-2 threshold.

static constexpr int BLOCK = 256;
static constexpr int PBLOCK = 512;                 // k_part block size
static constexpr int PGRID = 256;                  // k_part grid
static constexpr int BUCKET_BITS = 10;
static constexpr int BUCKET_NODES = 1 << BUCKET_BITS;
static constexpr int CAP = 16384;                  // mean 10240, sigma~101 -> +40 sigma

static constexpr float S1 = 65536.0f;              // layer-1 quant 2^16, bias +8
static constexpr float IS1 = 1.0f / 65536.0f;
static constexpr int   B1 = 8 * 65536;             // per-edge bias (2^19)
static constexpr float S2 = 16384.0f;              // layer-2 quant 2^14, bias +128
static constexpr float IS2 = 1.0f / 16384.0f;
static constexpr int   B2 = 128 * 16384;           // per-edge bias (2^21)

__global__ __launch_bounds__(512) void k_init(unsigned* __restrict__ cursor, int NB) {
    int b = blockIdx.x * 512 + threadIdx.x;
    if (b < NB) cursor[b] = (unsigned)b * (unsigned)CAP;
}

__global__ __launch_bounds__(PBLOCK) void k_part(
    const int* __restrict__ src, const int* __restrict__ dst,
    unsigned* __restrict__ cursor, unsigned* __restrict__ entries,
    int E, int NB)
{
    __shared__ unsigned hist[512];
    __shared__ unsigned base[512];
    int chunk = (E + gridDim.x - 1) / gridDim.x;
    int e0 = blockIdx.x * chunk;
    int e1 = min(e0 + chunk, E);

    for (int b = threadIdx.x; b < NB; b += PBLOCK) hist[b] = 0;
    __syncthreads();
    for (int e = e0 + (int)threadIdx.x; e < e1; e += PBLOCK)
        atomicAdd(&hist[((unsigned)dst[e]) >> BUCKET_BITS], 1u);
    __syncthreads();
    for (int b = threadIdx.x; b < NB; b += PBLOCK)
        base[b] = atomicAdd(&cursor[b], hist[b]);     // contiguous span claim
    __syncthreads();
    for (int b = threadIdx.x; b < NB; b += PBLOCK) hist[b] = 0;  // reuse as ranks
    __syncthreads();
    for (int e = e0 + (int)threadIdx.x; e < e1; e += PBLOCK) {
        unsigned d = (unsigned)dst[e];
        unsigned bk = d >> BUCKET_BITS;
        unsigned r = atomicAdd(&hist[bk], 1u);
        unsigned slot = base[bk] + r;
        unsigned lim = (bk + 1u) * (unsigned)CAP;
        if (slot < lim)   // statistically impossible to fail; guards OOB
            entries[slot] = ((unsigned)src[e] << BUCKET_BITS) | (d & (BUCKET_NODES - 1));
    }
}

__global__ __launch_bounds__(BLOCK) void k_agg1(
    const unsigned* __restrict__ entries, const unsigned* __restrict__ cursor,
    const float* __restrict__ x,
    const float* __restrict__ W1l, const float* __restrict__ b1,
    const float* __restrict__ W1r, const float* __restrict__ W2l,
    const float* __restrict__ W2r, const float* __restrict__ b2,
    unsigned* __restrict__ sq, float* __restrict__ t0a, float* __restrict__ inva,
    unsigned* __restrict__ dega, int N)
{
    __shared__ unsigned q0s[BUCKET_NODES], q1s[BUCKET_NODES], degs[BUCKET_NODES];
    int bk = blockIdx.x;
    for (int i = threadIdx.x; i < BUCKET_NODES; i += BLOCK) { q0s[i] = 0; q1s[i] = 0; degs[i] = 0; }
    __syncthreads();

    unsigned start = (unsigned)bk * (unsigned)CAP;
    unsigned end = min(cursor[bk], start + (unsigned)CAP);
    for (unsigned t = start + threadIdx.x; t < end; t += BLOCK) {
        unsigned en = entries[t];
        unsigned s = en >> BUCKET_BITS;
        unsigned dl = en & (BUCKET_NODES - 1);
        float2 xv = *reinterpret_cast<const float2*>(x + 2 * (size_t)s);
        unsigned q0 = (unsigned)__float2int_rn((xv.x + 8.0f) * S1);  // < 2^20
        unsigned q1 = (unsigned)__float2int_rn((xv.y + 8.0f) * S1);
        atomicAdd(&q0s[dl], q0);
        atomicAdd(&q1s[dl], q1);
        atomicAdd(&degs[dl], 1u);
    }
    __syncthreads();

    int nodebase = bk << BUCKET_BITS;
    for (int il = threadIdx.x; il < BUCKET_NODES; il += BLOCK) {
        int i = nodebase + il;
        if (i >= N) continue;
        int deg = (int)degs[il];
        float inv = 1.0f / (float)max(deg, 1);
        float m0 = (float)((int)q0s[il] - deg * B1) * IS1 * inv;
        float m1 = (float)((int)q1s[il] - deg * B1) * IS1 * inv;
        float2 xv = *reinterpret_cast<const float2*>(x + 2 * (size_t)i);
        float s = 0.0f, t0 = b2[0];
#pragma unroll
        for (int o = 0; o < 16; ++o) {
            float h = m0 * W1l[2 * o] + m1 * W1l[2 * o + 1] + b1[o]
                    + xv.x * W1r[2 * o] + xv.y * W1r[2 * o + 1];
            h = fmaxf(h, 0.0f);
            s  += h * W2l[o];
            t0 += h * W2r[o];
        }
        sq[i]   = (unsigned)__float2int_rn((s + 128.0f) * S2);  // |s|<=77 -> < 2^22
        t0a[i]  = t0;
        inva[i] = inv;
        dega[i] = (unsigned)deg;
    }
}

__global__ __launch_bounds__(BLOCK) void k_agg2(
    const unsigned* __restrict__ entries, const unsigned* __restrict__ cursor,
    const unsigned* __restrict__ sq,
    const float* __restrict__ t0a, const float* __restrict__ inva,
    const unsigned* __restrict__ dega,
    float* __restrict__ out, int N)
{
    __shared__ unsigned sbin[BUCKET_NODES];
    int bk = blockIdx.x;
    for (int i = threadIdx.x; i < BUCKET_NODES; i += BLOCK) sbin[i] = 0;
    __syncthreads();

    unsigned start = (unsigned)bk * (unsigned)CAP;
    unsigned end = min(cursor[bk], start + (unsigned)CAP);
    for (unsigned t = start + threadIdx.x; t < end; t += BLOCK) {
        unsigned en = entries[t];
        unsigned s = en >> BUCKET_BITS;
        unsigned dl = en & (BUCKET_NODES - 1);
        atomicAdd(&sbin[dl], sq[s]);   // sum < 63 * 2^22 < 2^28
    }
    __syncthreads();

    int nodebase = bk << BUCKET_BITS;
    for (int il = threadIdx.x; il < BUCKET_NODES; il += BLOCK) {
        int i = nodebase + il;
        if (i >= N) continue;
        int deg = (int)dega[i];
        float mean_s = (float)((int)sbin[il] - deg * B2) * IS2 * inva[i];
        float t = mean_s + t0a[i];
        out[i] = 1.0f / (1.0f + expf(-t));
    }
}

// ------------------- fallback (simple atomic path, 10MB ws) -----------------
__global__ __launch_bounds__(256) void k_scatter1_fb(
    const int* __restrict__ src, const int* __restrict__ dst,
    const float* __restrict__ x, float* __restrict__ agg1, float* __restrict__ deg, int E)
{
    int stride = gridDim.x * blockDim.x;
    for (int e = blockIdx.x * blockDim.x + threadIdx.x; e < E; e += stride) {
        int s = src[e], d = dst[e];
        float2 xv = *reinterpret_cast<const float2*>(x + 2 * (size_t)s);
        unsafeAtomicAdd(&agg1[2 * (size_t)d + 0], xv.x);
        unsafeAtomicAdd(&agg1[2 * (size_t)d + 1], xv.y);
        unsafeAtomicAdd(&deg[d], 1.0f);
    }
}
__global__ __launch_bounds__(256) void k_node1_fb(
    const float* __restrict__ x, const float* __restrict__ agg1, const float* __restrict__ deg,
    const float* __restrict__ W1l, const float* __restrict__ b1,
    const float* __restrict__ W1r, const float* __restrict__ W2l,
    float* __restrict__ sval, int N)
{
    int i = blockIdx.x * blockDim.x + threadIdx.x;
    if (i >= N) return;
    float inv = 1.0f / fmaxf(deg[i], 1.0f);
    float2 a = *reinterpret_cast<const float2*>(agg1 + 2 * (size_t)i);
    float m0 = a.x * inv, m1 = a.y * inv;
    float2 xv = *reinterpret_cast<const float2*>(x + 2 * (size_t)i);
    float s = 0.0f;
#pragma unroll
    for (int o = 0; o < 16; ++o) {
        float h = m0 * W1l[2 * o] + m1 * W1l[2 * o + 1] + b1[o]
                + xv.x * W1r[2 * o] + xv.y * W1r[2 * o + 1];
        s += fmaxf(h, 0.0f) * W2l[o];
    }
    sval[i] = s;
}
__global__ __launch_bounds__(256) void k_scatter2_fb(
    const int* __restrict__ src, const int* __restrict__ dst,
    const float* __restrict__ sval, float* __restrict__ agg_s, int E)
{
    int stride = gridDim.x * blockDim.x;
    for (int e = blockIdx.x * blockDim.x + threadIdx.x; e < E; e += stride)
        unsafeAtomicAdd(&agg_s[dst[e]], sval[src[e]]);
}
__global__ __launch_bounds__(256) void k_node2_fb(
    const float* __restrict__ x, const float* __restrict__ agg1, const float* __restrict__ deg,
    const float* __restrict__ agg_s,
    const float* __restrict__ W1l, const float* __restrict__ b1,
    const float* __restrict__ W1r, const float* __restrict__ W2r, const float* __restrict__ b2,
    float* __restrict__ out, int N)
{
    int i = blockIdx.x * blockDim.x + threadIdx.x;
    if (i >= N) return;
    float inv = 1.0f / fmaxf(deg[i], 1.0f);
    float2 a = *reinterpret_cast<const float2*>(agg1 + 2 * (size_t)i);
    float m0 = a.x * inv, m1 = a.y * inv;
    float2 xv = *reinterpret_cast<const float2*>(x + 2 * (size_t)i);
    float t = agg_s[i] * inv + b2[0];
#pragma unroll
    for (int o = 0; o < 16; ++o) {
        float h = m0 * W1l[2 * o] + m1 * W1l[2 * o + 1] + b1[o]
                + xv.x * W1r[2 * o] + xv.y * W1r[2 * o + 1];
        t += fmaxf(h, 0.0f) * W2r[o];
    }
    out[i] = 1.0f / (1.0f + expf(-t));
}

extern "C" void kernel_launch(void* const* d_in, const int* in_sizes, int n_in,
                              void* d_out, int out_size, void* d_ws, size_t ws_size,
                              hipStream_t stream) {
    const float* x   = (const float*)d_in[0];
    const int*   ei  = (const int*)d_in[1];
    const float* W1l = (const float*)d_in[2];
    const float* b1  = (const float*)d_in[3];
    const float* W1r = (const float*)d_in[4];
    const float* W2l = (const float*)d_in[5];
    const float* b2  = (const float*)d_in[6];
    const float* W2r = (const float*)d_in[7];

    const int N = in_sizes[0] / 2;
    const int E = in_sizes[1] / 2;
    const int* src = ei;
    const int* dst = ei + (size_t)E;
    float* out = (float*)d_out;

    const int NB = (N + BUCKET_NODES - 1) >> BUCKET_BITS;

    // ws: cursor[512] | entries[NB*CAP] | sq[N] | t0a[N] | inva[N] | dega[N]
    size_t needed = 512 * 4 + (size_t)NB * CAP * 4 + 4 * (size_t)N * 4;
    if (NB <= 512 && ws_size >= needed) {
        unsigned* cursor  = (unsigned*)d_ws;
        unsigned* entries = cursor + 512;
        unsigned* sq      = entries + (size_t)NB * CAP;
        float*    t0a     = (float*)(sq + N);
        float*    inva    = t0a + N;
        unsigned* dega    = (unsigned*)(inva + N);

        k_init<<<(NB + 511) / 512, 512, 0, stream>>>(cursor, NB);
        k_part<<<PGRID, PBLOCK, 0, stream>>>(src, dst, cursor, entries, E, NB);
        k_agg1<<<NB, BLOCK, 0, stream>>>(entries, cursor, x, W1l, b1, W1r, W2l, W2r, b2,
                                         sq, t0a, inva, dega, N);
        k_agg2<<<NB, BLOCK, 0, stream>>>(entries, cursor, sq, t0a, inva, dega, out, N);
    } else {
        float* agg1  = (float*)d_ws;
        float* deg   = agg1 + 2 * (size_t)N;
        float* agg_s = deg + (size_t)N;
        float* sval  = agg_s + (size_t)N;
        hipMemsetAsync(d_ws, 0, 4 * (size_t)N * sizeof(float), stream);
        const int eblocks = 2048, nblocks = (N + 255) / 256;
        k_scatter1_fb<<<eblocks, 256, 0, stream>>>(src, dst, x, agg1, deg, E);
        k_node1_fb<<<nblocks, 256, 0, stream>>>(x, agg1, deg, W1l, b1, W1r, W2l, sval, N);
        k_scatter2_fb<<<eblocks, 256, 0, stream>>>(src, dst, sval, agg_s, E);
        k_node2_fb<<<nblocks, 256, 0, stream>>>(x, agg1, deg, agg_s, W1l, b1, W1r, W2r, b2, out, N);
    }
}

// Round 4
// 112.114 us; speedup vs baseline: 8.8662x; 1.0997x over previous
//
#include <hip/hip_runtime.h>

// GraphSAGE 2-layer, N=500000, E=5000000.
// Pipeline: k_init -> k_part (bucket partition by dst>>10) -> k_agg1 (LDS
// integer bins + fused node MLP) -> k_agg2 (LDS scalar bins + fused sigmoid).
// Round-4 changes:
//  - cursor padded to 64B/bucket + rotated claim order (round-3: all blocks'
//    claim atomics serialized on 32 cache lines -> ~80us)
//  - k_part caches chunk's dst in LDS (2nd pass reads only src from HBM)
//  - k_part block 512->1024 (16 waves/CU latency hiding)
//  - k_agg1 packs (deg,q0,q1) into ONE u64 LDS atomic per edge (was 3 u32)
// All aggregation fixed-point integer => deterministic; quant err ~1e-4.

static constexpr int BLOCK = 256;
static constexpr int PBLOCK = 1024;
static constexpr int PGRID = 256;
static constexpr int BUCKET_BITS = 10;
static constexpr int BUCKET_NODES = 1 << BUCKET_BITS;
static constexpr int CAP = 16384;            // mean 10240, sigma~101
static constexpr int CSTRIDE = 16;           // cursor padding: 16 u32 = 64B
static constexpr int MAXCHUNK = 19584;       // >= ceil(5M/256)

static constexpr float S1 = 65536.0f;        // layer-1 quant 2^16, bias +8
static constexpr float IS1 = 1.0f / 65536.0f;
static constexpr long long B1 = 8LL * 65536LL;
static constexpr float S2 = 16384.0f;        // layer-2 quant 2^14, bias +128
static constexpr float IS2 = 1.0f / 16384.0f;
static constexpr int   B2 = 128 * 16384;

__global__ __launch_bounds__(512) void k_init(unsigned* __restrict__ cursor, int NB) {
    int b = blockIdx.x * 512 + threadIdx.x;
    if (b < NB) cursor[(size_t)b * CSTRIDE] = (unsigned)b * (unsigned)CAP;
}

__global__ __launch_bounds__(PBLOCK) void k_part(
    const int* __restrict__ src, const int* __restrict__ dst,
    unsigned* __restrict__ cursor, unsigned* __restrict__ entries,
    int E, int NB)
{
    __shared__ unsigned dstc[MAXCHUNK];
    __shared__ unsigned hist[512];
    __shared__ unsigned base[512];
    int chunk = (E + gridDim.x - 1) / gridDim.x;
    int e0 = blockIdx.x * chunk;
    int e1 = min(e0 + chunk, E);
    int n = e1 - e0;

    for (int b = threadIdx.x; b < NB; b += PBLOCK) hist[b] = 0;
    __syncthreads();
    // pass 1: histogram + cache dst in LDS
    for (int t = threadIdx.x; t < n; t += PBLOCK) {
        unsigned d = (unsigned)dst[e0 + t];
        dstc[t] = d;
        atomicAdd(&hist[d >> BUCKET_BITS], 1u);
    }
    __syncthreads();
    // claim contiguous spans; rotate order by block to spread line traffic
    for (int b0 = threadIdx.x; b0 < NB; b0 += PBLOCK) {
        int b = b0 + (int)(blockIdx.x % (unsigned)NB);
        if (b >= NB) b -= NB;
        base[b] = atomicAdd(&cursor[(size_t)b * CSTRIDE], hist[b]);
    }
    __syncthreads();
    for (int b = threadIdx.x; b < NB; b += PBLOCK) hist[b] = 0;  // reuse as ranks
    __syncthreads();
    // pass 2: scatter entries (src from HBM, dst from LDS)
    for (int t = threadIdx.x; t < n; t += PBLOCK) {
        unsigned d = dstc[t];
        unsigned bk = d >> BUCKET_BITS;
        unsigned r = atomicAdd(&hist[bk], 1u);
        unsigned slot = base[bk] + r;
        unsigned lim = (bk + 1u) * (unsigned)CAP;
        if (slot < lim)
            entries[slot] = ((unsigned)src[e0 + t] << BUCKET_BITS) | (d & (BUCKET_NODES - 1));
    }
}

__global__ __launch_bounds__(BLOCK) void k_agg1(
    const unsigned* __restrict__ entries, const unsigned* __restrict__ cursor,
    const float* __restrict__ x,
    const float* __restrict__ W1l, const float* __restrict__ b1,
    const float* __restrict__ W1r, const float* __restrict__ W2l,
    const float* __restrict__ W2r, const float* __restrict__ b2,
    unsigned* __restrict__ sq, float* __restrict__ t0a, float* __restrict__ inva,
    unsigned* __restrict__ dega, int N)
{
    __shared__ unsigned long long qs[BUCKET_NODES];   // deg[63:56]|q0[55:28]|q1[27:0]
    int bk = blockIdx.x;
    for (int i = threadIdx.x; i < BUCKET_NODES; i += BLOCK) qs[i] = 0ULL;
    __syncthreads();

    unsigned start = (unsigned)bk * (unsigned)CAP;
    unsigned end = min(cursor[(size_t)bk * CSTRIDE], start + (unsigned)CAP);
    for (unsigned t = start + threadIdx.x; t < end; t += BLOCK) {
        unsigned en = entries[t];
        unsigned s = en >> BUCKET_BITS;
        unsigned dl = en & (BUCKET_NODES - 1);
        float2 xv = *reinterpret_cast<const float2*>(x + 2 * (size_t)s);
        unsigned q0 = (unsigned)__float2int_rn((xv.x + 8.0f) * S1);  // < 2^20
        unsigned q1 = (unsigned)__float2int_rn((xv.y + 8.0f) * S1);
        unsigned long long pk = (1ULL << 56) | ((unsigned long long)q0 << 28)
                              | (unsigned long long)q1;
        atomicAdd(&qs[dl], pk);
    }
    __syncthreads();

    int nodebase = bk << BUCKET_BITS;
    for (int il = threadIdx.x; il < BUCKET_NODES; il += BLOCK) {
        int i = nodebase + il;
        if (i >= N) continue;
        unsigned long long v = qs[il];
        int deg = (int)(v >> 56);
        long long q0 = (long long)((v >> 28) & 0xFFFFFFFULL);
        long long q1 = (long long)(v & 0xFFFFFFFULL);
        long long bias = (long long)deg * B1;
        float inv = 1.0f / (float)max(deg, 1);
        float m0 = (float)(q0 - bias) * IS1 * inv;
        float m1 = (float)(q1 - bias) * IS1 * inv;
        float2 xv = *reinterpret_cast<const float2*>(x + 2 * (size_t)i);
        float s = 0.0f, t0 = b2[0];
#pragma unroll
        for (int o = 0; o < 16; ++o) {
            float h = m0 * W1l[2 * o] + m1 * W1l[2 * o + 1] + b1[o]
                    + xv.x * W1r[2 * o] + xv.y * W1r[2 * o + 1];
            h = fmaxf(h, 0.0f);
            s  += h * W2l[o];
            t0 += h * W2r[o];
        }
        sq[i]   = (unsigned)__float2int_rn((s + 128.0f) * S2);  // < 2^22
        t0a[i]  = t0;
        inva[i] = inv;
        dega[i] = (unsigned)deg;
    }
}

__global__ __launch_bounds__(BLOCK) void k_agg2(
    const unsigned* __restrict__ entries, const unsigned* __restrict__ cursor,
    const unsigned* __restrict__ sq,
    const float* __restrict__ t0a, const float* __restrict__ inva,
    const unsigned* __restrict__ dega,
    float* __restrict__ out, int N)
{
    __shared__ unsigned sbin[BUCKET_NODES];
    int bk = blockIdx.x;
    for (int i = threadIdx.x; i < BUCKET_NODES; i += BLOCK) sbin[i] = 0;
    __syncthreads();

    unsigned start = (unsigned)bk * (unsigned)CAP;
    unsigned end = min(cursor[(size_t)bk * CSTRIDE], start + (unsigned)CAP);
    for (unsigned t = start + threadIdx.x; t < end; t += BLOCK) {
        unsigned en = entries[t];
        unsigned s = en >> BUCKET_BITS;
        unsigned dl = en & (BUCKET_NODES - 1);
        atomicAdd(&sbin[dl], sq[s]);   // sum < 64 * 2^22 < 2^28
    }
    __syncthreads();

    int nodebase = bk << BUCKET_BITS;
    for (int il = threadIdx.x; il < BUCKET_NODES; il += BLOCK) {
        int i = nodebase + il;
        if (i >= N) continue;
        int deg = (int)dega[i];
        float mean_s = (float)((int)sbin[il] - deg * B2) * IS2 * inva[i];
        out[i] = 1.0f / (1.0f + expf(-(mean_s + t0a[i])));
    }
}

// ------------------- fallback (simple atomic path, 10MB ws) -----------------
__global__ __launch_bounds__(256) void k_scatter1_fb(
    const int* __restrict__ src, const int* __restrict__ dst,
    const float* __restrict__ x, float* __restrict__ agg1, float* __restrict__ deg, int E)
{
    int stride = gridDim.x * blockDim.x;
    for (int e = blockIdx.x * blockDim.x + threadIdx.x; e < E; e += stride) {
        int s = src[e], d = dst[e];
        float2 xv = *reinterpret_cast<const float2*>(x + 2 * (size_t)s);
        unsafeAtomicAdd(&agg1[2 * (size_t)d + 0], xv.x);
        unsafeAtomicAdd(&agg1[2 * (size_t)d + 1], xv.y);
        unsafeAtomicAdd(&deg[d], 1.0f);
    }
}
__global__ __launch_bounds__(256) void k_node1_fb(
    const float* __restrict__ x, const float* __restrict__ agg1, const float* __restrict__ deg,
    const float* __restrict__ W1l, const float* __restrict__ b1,
    const float* __restrict__ W1r, const float* __restrict__ W2l,
    float* __restrict__ sval, int N)
{
    int i = blockIdx.x * blockDim.x + threadIdx.x;
    if (i >= N) return;
    float inv = 1.0f / fmaxf(deg[i], 1.0f);
    float2 a = *reinterpret_cast<const float2*>(agg1 + 2 * (size_t)i);
    float m0 = a.x * inv, m1 = a.y * inv;
    float2 xv = *reinterpret_cast<const float2*>(x + 2 * (size_t)i);
    float s = 0.0f;
#pragma unroll
    for (int o = 0; o < 16; ++o) {
        float h = m0 * W1l[2 * o] + m1 * W1l[2 * o + 1] + b1[o]
                + xv.x * W1r[2 * o] + xv.y * W1r[2 * o + 1];
        s += fmaxf(h, 0.0f) * W2l[o];
    }
    sval[i] = s;
}
__global__ __launch_bounds__(256) void k_scatter2_fb(
    const int* __restrict__ src, const int* __restrict__ dst,
    const float* __restrict__ sval, float* __restrict__ agg_s, int E)
{
    int stride = gridDim.x * blockDim.x;
    for (int e = blockIdx.x * blockDim.x + threadIdx.x; e < E; e += stride)
        unsafeAtomicAdd(&agg_s[dst[e]], sval[src[e]]);
}
__global__ __launch_bounds__(256) void k_node2_fb(
    const float* __restrict__ x, const float* __restrict__ agg1, const float* __restrict__ deg,
    const float* __restrict__ agg_s,
    const float* __restrict__ W1l, const float* __restrict__ b1,
    const float* __restrict__ W1r, const float* __restrict__ W2r, const float* __restrict__ b2,
    float* __restrict__ out, int N)
{
    int i = blockIdx.x * blockDim.x + threadIdx.x;
    if (i >= N) return;
    float inv = 1.0f / fmaxf(deg[i], 1.0f);
    float2 a = *reinterpret_cast<const float2*>(agg1 + 2 * (size_t)i);
    float m0 = a.x * inv, m1 = a.y * inv;
    float2 xv = *reinterpret_cast<const float2*>(x + 2 * (size_t)i);
    float t = agg_s[i] * inv + b2[0];
#pragma unroll
    for (int o = 0; o < 16; ++o) {
        float h = m0 * W1l[2 * o] + m1 * W1l[2 * o + 1] + b1[o]
                + xv.x * W1r[2 * o] + xv.y * W1r[2 * o + 1];
        t += fmaxf(h, 0.0f) * W2r[o];
    }
    out[i] = 1.0f / (1.0f + expf(-t));
}

extern "C" void kernel_launch(void* const* d_in, const int* in_sizes, int n_in,
                              void* d_out, int out_size, void* d_ws, size_t ws_size,
                              hipStream_t stream) {
    const float* x   = (const float*)d_in[0];
    const int*   ei  = (const int*)d_in[1];
    const float* W1l = (const float*)d_in[2];
    const float* b1  = (const float*)d_in[3];
    const float* W1r = (const float*)d_in[4];
    const float* W2l = (const float*)d_in[5];
    const float* b2  = (const float*)d_in[6];
    const float* W2r = (const float*)d_in[7];

    const int N = in_sizes[0] / 2;
    const int E = in_sizes[1] / 2;
    const int* src = ei;
    const int* dst = ei + (size_t)E;
    float* out = (float*)d_out;

    const int NB = (N + BUCKET_NODES - 1) >> BUCKET_BITS;
    const int chunk = (E + PGRID - 1) / PGRID;

    // ws: cursor[512*16] | entries[NB*CAP] | sq[N] | t0a[N] | inva[N] | dega[N]
    size_t needed = 512 * CSTRIDE * 4 + (size_t)NB * CAP * 4 + 4 * (size_t)N * 4;
    if (NB <= 512 && chunk <= MAXCHUNK && ws_size >= needed) {
        unsigned* cursor  = (unsigned*)d_ws;
        unsigned* entries = cursor + 512 * CSTRIDE;
        unsigned* sq      = entries + (size_t)NB * CAP;
        float*    t0a     = (float*)(sq + N);
        float*    inva    = t0a + N;
        unsigned* dega    = (unsigned*)(inva + N);

        k_init<<<(NB + 511) / 512, 512, 0, stream>>>(cursor, NB);
        k_part<<<PGRID, PBLOCK, 0, stream>>>(src, dst, cursor, entries, E, NB);
        k_agg1<<<NB, BLOCK, 0, stream>>>(entries, cursor, x, W1l, b1, W1r, W2l, W2r, b2,
                                         sq, t0a, inva, dega, N);
        k_agg2<<<NB, BLOCK, 0, stream>>>(entries, cursor, sq, t0a, inva, dega, out, N);
    } else {
        float* agg1  = (float*)d_ws;
        float* deg   = agg1 + 2 * (size_t)N;
        float* agg_s = deg + (size_t)N;
        float* sval  = agg_s + (size_t)N;
        hipMemsetAsync(d_ws, 0, 4 * (size_t)N * sizeof(float), stream);
        const int eblocks = 2048, nblocks = (N + 255) / 256;
        k_scatter1_fb<<<eblocks, 256, 0, stream>>>(src, dst, x, agg1, deg, E);
        k_node1_fb<<<nblocks, 256, 0, stream>>>(x, agg1, deg, W1l, b1, W1r, W2l, sval, N);
        k_scatter2_fb<<<eblocks, 256, 0, stream>>>(src, dst, sval, agg_s, E);
        k_node2_fb<<<nblocks, 256, 0, stream>>>(x, agg1, deg, agg_s, W1l, b1, W1r, W2r, b2, out, N);
    }
}

// Round 5
// 94.988 us; speedup vs baseline: 10.4648x; 1.1803x over previous
//
#include <hip/hip_runtime.h>

// GraphSAGE 2-layer, N=500000, E=5000000.
// Pipeline: k_init -> k_part (bucket partition by dst>>10, block-local
// counting sort in LDS, coalesced run flush) -> k_agg1 (LDS u64 bins +
// fused node MLP) -> k_agg2 (LDS u32 bins + fused sigmoid).
// Round-5: int4-vectorized edge loads (4x ILP vs scalar: k_part was
// latency-bound at VALUBusy 4%), LDS counting sort + coalesced entry flush
// (was 5M random 4B stores, 3.7x write amplification), 512-thread agg blocks.
// All aggregation fixed-point integer => deterministic; quant err ~1e-4.

static constexpr int ABLOCK = 512;           // agg kernels block size
static constexpr int PBLOCK = 1024;
static constexpr int PGRID = 256;
static constexpr int BUCKET_BITS = 10;
static constexpr int BUCKET_NODES = 1 << BUCKET_BITS;
static constexpr int CAP = 16384;            // mean 10240, sigma~101
static constexpr int CSTRIDE = 16;           // cursor padding: 64B
static constexpr int MAXCHUNK = 19584;       // >= ceil(5M/256), mult of 4

static constexpr float S1 = 65536.0f;        // layer-1 quant 2^16, bias +8
static constexpr float IS1 = 1.0f / 65536.0f;
static constexpr long long B1 = 8LL * 65536LL;
static constexpr float S2 = 16384.0f;        // layer-2 quant 2^14, bias +128
static constexpr float IS2 = 1.0f / 16384.0f;
static constexpr int   B2 = 128 * 16384;

__global__ __launch_bounds__(512) void k_init(unsigned* __restrict__ cursor, int NB) {
    int b = blockIdx.x * 512 + threadIdx.x;
    if (b < NB) cursor[(size_t)b * CSTRIDE] = (unsigned)b * (unsigned)CAP;
}

__global__ __launch_bounds__(PBLOCK) void k_part(
    const int* __restrict__ src, const int* __restrict__ dst,
    unsigned* __restrict__ cursor, unsigned* __restrict__ entries,
    int E, int NB)
{
    __shared__ unsigned sorted[MAXCHUNK];
    __shared__ unsigned hist[512];
    __shared__ unsigned loc[512];
    __shared__ unsigned base[512];
    const int tid = threadIdx.x;
    const int chunk = (E + gridDim.x - 1) / gridDim.x;
    const int e0 = blockIdx.x * chunk;
    const int e1 = min(e0 + chunk, E);
    const int n = e1 - e0;
    const int nv = n >> 2;                       // int4 groups
    const int4* dst4 = reinterpret_cast<const int4*>(dst + e0);
    const int4* src4 = reinterpret_cast<const int4*>(src + e0);

    for (int b = tid; b < 512; b += PBLOCK) hist[b] = 0;
    __syncthreads();

    // ---- pass 1: histogram (4 edges/thread/iter) ----
    for (int t = tid; t < nv; t += PBLOCK) {
        int4 d = dst4[t];
        atomicAdd(&hist[(unsigned)d.x >> BUCKET_BITS], 1u);
        atomicAdd(&hist[(unsigned)d.y >> BUCKET_BITS], 1u);
        atomicAdd(&hist[(unsigned)d.z >> BUCKET_BITS], 1u);
        atomicAdd(&hist[(unsigned)d.w >> BUCKET_BITS], 1u);
    }
    for (int e = e0 + (nv << 2) + tid; e < e1; e += PBLOCK)
        atomicAdd(&hist[(unsigned)dst[e] >> BUCKET_BITS], 1u);
    __syncthreads();

    // ---- block-level exclusive prefix sum (Hillis-Steele, NB<=512<=PBLOCK) --
    if (tid < NB) loc[tid] = hist[tid];
    __syncthreads();
    for (int off = 1; off < NB; off <<= 1) {
        unsigned v = 0;
        if (tid < NB && tid >= off) v = loc[tid - off];
        __syncthreads();
        if (tid < NB) loc[tid] += v;
        __syncthreads();
    }
    if (tid < NB) loc[tid] -= hist[tid];         // inclusive -> exclusive

    // ---- claim contiguous global spans (rotated; cursor lines padded) ----
    if (tid < NB) {
        int b = tid + (int)(blockIdx.x % (unsigned)NB);
        if (b >= NB) b -= NB;
        base[b] = atomicAdd(&cursor[(size_t)b * CSTRIDE], hist[b]);
    }
    __syncthreads();
    for (int b = tid; b < 512; b += PBLOCK) hist[b] = 0;   // reuse as ranks
    __syncthreads();

    // ---- pass 2: scatter into LDS-sorted order (4 edges/thread/iter) ----
    for (int t = tid; t < nv; t += PBLOCK) {
        int4 d = dst4[t];
        int4 s = src4[t];
        {
            unsigned bk = (unsigned)d.x >> BUCKET_BITS;
            unsigned r = atomicAdd(&hist[bk], 1u);
            sorted[loc[bk] + r] = ((unsigned)s.x << BUCKET_BITS) | ((unsigned)d.x & (BUCKET_NODES - 1));
        }
        {
            unsigned bk = (unsigned)d.y >> BUCKET_BITS;
            unsigned r = atomicAdd(&hist[bk], 1u);
            sorted[loc[bk] + r] = ((unsigned)s.y << BUCKET_BITS) | ((unsigned)d.y & (BUCKET_NODES - 1));
        }
        {
            unsigned bk = (unsigned)d.z >> BUCKET_BITS;
            unsigned r = atomicAdd(&hist[bk], 1u);
            sorted[loc[bk] + r] = ((unsigned)s.z << BUCKET_BITS) | ((unsigned)d.z & (BUCKET_NODES - 1));
        }
        {
            unsigned bk = (unsigned)d.w >> BUCKET_BITS;
            unsigned r = atomicAdd(&hist[bk], 1u);
            sorted[loc[bk] + r] = ((unsigned)s.w << BUCKET_BITS) | ((unsigned)d.w & (BUCKET_NODES - 1));
        }
    }
    for (int e = e0 + (nv << 2) + tid; e < e1; e += PBLOCK) {
        unsigned d = (unsigned)dst[e];
        unsigned bk = d >> BUCKET_BITS;
        unsigned r = atomicAdd(&hist[bk], 1u);
        sorted[loc[bk] + r] = ((unsigned)src[e] << BUCKET_BITS) | (d & (BUCKET_NODES - 1));
    }
    __syncthreads();

    // ---- pass 3: coalesced flush, one bucket run per wave ----
    const int wave = tid >> 6, lane = tid & 63;
    const int nw = PBLOCK >> 6;
    const int off = (int)(blockIdx.x % (unsigned)NB);
    for (int j = wave; j < NB; j += nw) {
        int b = j + off;
        if (b >= NB) b -= NB;
        unsigned cnt = hist[b];
        if (cnt == 0) continue;
        unsigned lo = loc[b], ba = base[b];
        unsigned lim = (unsigned)(b + 1) * (unsigned)CAP;
        if (ba >= lim) continue;                 // overflow guard (stat. impossible)
        cnt = min(cnt, lim - ba);
        for (unsigned i = lane; i < cnt; i += 64)
            entries[ba + i] = sorted[lo + i];
    }
}

__global__ __launch_bounds__(ABLOCK) void k_agg1(
    const unsigned* __restrict__ entries, const unsigned* __restrict__ cursor,
    const float* __restrict__ x,
    const float* __restrict__ W1l, const float* __restrict__ b1,
    const float* __restrict__ W1r, const float* __restrict__ W2l,
    const float* __restrict__ W2r, const float* __restrict__ b2,
    unsigned* __restrict__ sq, float* __restrict__ t0a, float* __restrict__ inva,
    unsigned* __restrict__ dega, int N)
{
    __shared__ unsigned long long qs[BUCKET_NODES];  // deg[63:56]|q0[55:28]|q1[27:0]
    int bk = blockIdx.x;
    for (int i = threadIdx.x; i < BUCKET_NODES; i += ABLOCK) qs[i] = 0ULL;
    __syncthreads();

    unsigned start = (unsigned)bk * (unsigned)CAP;
    unsigned end = min(cursor[(size_t)bk * CSTRIDE], start + (unsigned)CAP);
    unsigned n = end - start;
    unsigned nv = n >> 2;
    const uint4* e4 = reinterpret_cast<const uint4*>(entries + start);

    #define PROC1(en) { \
        unsigned s_ = (en) >> BUCKET_BITS; \
        unsigned dl_ = (en) & (BUCKET_NODES - 1); \
        float2 xv_ = *reinterpret_cast<const float2*>(x + 2 * (size_t)s_); \
        unsigned q0_ = (unsigned)__float2int_rn((xv_.x + 8.0f) * S1); \
        unsigned q1_ = (unsigned)__float2int_rn((xv_.y + 8.0f) * S1); \
        atomicAdd(&qs[dl_], (1ULL << 56) | ((unsigned long long)q0_ << 28) | (unsigned long long)q1_); }

    for (unsigned t = threadIdx.x; t < nv; t += ABLOCK) {
        uint4 en = e4[t];
        PROC1(en.x) PROC1(en.y) PROC1(en.z) PROC1(en.w)
    }
    for (unsigned t = start + (nv << 2) + threadIdx.x; t < end; t += ABLOCK) {
        unsigned en = entries[t];
        PROC1(en)
    }
    #undef PROC1
    __syncthreads();

    int nodebase = bk << BUCKET_BITS;
    for (int il = threadIdx.x; il < BUCKET_NODES; il += ABLOCK) {
        int i = nodebase + il;
        if (i >= N) continue;
        unsigned long long v = qs[il];
        int deg = (int)(v >> 56);
        long long q0 = (long long)((v >> 28) & 0xFFFFFFFULL);
        long long q1 = (long long)(v & 0xFFFFFFFULL);
        long long bias = (long long)deg * B1;
        float inv = 1.0f / (float)max(deg, 1);
        float m0 = (float)(q0 - bias) * IS1 * inv;
        float m1 = (float)(q1 - bias) * IS1 * inv;
        float2 xv = *reinterpret_cast<const float2*>(x + 2 * (size_t)i);
        float s = 0.0f, t0 = b2[0];
#pragma unroll
        for (int o = 0; o < 16; ++o) {
            float h = m0 * W1l[2 * o] + m1 * W1l[2 * o + 1] + b1[o]
                    + xv.x * W1r[2 * o] + xv.y * W1r[2 * o + 1];
            h = fmaxf(h, 0.0f);
            s  += h * W2l[o];
            t0 += h * W2r[o];
        }
        sq[i]   = (unsigned)__float2int_rn((s + 128.0f) * S2);  // < 2^22
        t0a[i]  = t0;
        inva[i] = inv;
        dega[i] = (unsigned)deg;
    }
}

__global__ __launch_bounds__(ABLOCK) void k_agg2(
    const unsigned* __restrict__ entries, const unsigned* __restrict__ cursor,
    const unsigned* __restrict__ sq,
    const float* __restrict__ t0a, const float* __restrict__ inva,
    const unsigned* __restrict__ dega,
    float* __restrict__ out, int N)
{
    __shared__ unsigned sbin[BUCKET_NODES];
    int bk = blockIdx.x;
    for (int i = threadIdx.x; i < BUCKET_NODES; i += ABLOCK) sbin[i] = 0;
    __syncthreads();

    unsigned start = (unsigned)bk * (unsigned)CAP;
    unsigned end = min(cursor[(size_t)bk * CSTRIDE], start + (unsigned)CAP);
    unsigned n = end - start;
    unsigned nv = n >> 2;
    const uint4* e4 = reinterpret_cast<const uint4*>(entries + start);

    #define PROC2(en) { \
        unsigned s_ = (en) >> BUCKET_BITS; \
        unsigned dl_ = (en) & (BUCKET_NODES - 1); \
        atomicAdd(&sbin[dl_], sq[s_]); }

    for (unsigned t = threadIdx.x; t < nv; t += ABLOCK) {
        uint4 en = e4[t];
        PROC2(en.x) PROC2(en.y) PROC2(en.z) PROC2(en.w)
    }
    for (unsigned t = start + (nv << 2) + threadIdx.x; t < end; t += ABLOCK) {
        unsigned en = entries[t];
        PROC2(en)
    }
    #undef PROC2
    __syncthreads();

    int nodebase = bk << BUCKET_BITS;
    for (int il = threadIdx.x; il < BUCKET_NODES; il += ABLOCK) {
        int i = nodebase + il;
        if (i >= N) continue;
        int deg = (int)dega[i];
        float mean_s = (float)((int)sbin[il] - deg * B2) * IS2 * inva[i];
        out[i] = 1.0f / (1.0f + expf(-(mean_s + t0a[i])));
    }
}

// ------------------- fallback (simple atomic path, 10MB ws) -----------------
__global__ __launch_bounds__(256) void k_scatter1_fb(
    const int* __restrict__ src, const int* __restrict__ dst,
    const float* __restrict__ x, float* __restrict__ agg1, float* __restrict__ deg, int E)
{
    int stride = gridDim.x * blockDim.x;
    for (int e = blockIdx.x * blockDim.x + threadIdx.x; e < E; e += stride) {
        int s = src[e], d = dst[e];
        float2 xv = *reinterpret_cast<const float2*>(x + 2 * (size_t)s);
        unsafeAtomicAdd(&agg1[2 * (size_t)d + 0], xv.x);
        unsafeAtomicAdd(&agg1[2 * (size_t)d + 1], xv.y);
        unsafeAtomicAdd(&deg[d], 1.0f);
    }
}
__global__ __launch_bounds__(256) void k_node1_fb(
    const float* __restrict__ x, const float* __restrict__ agg1, const float* __restrict__ deg,
    const float* __restrict__ W1l, const float* __restrict__ b1,
    const float* __restrict__ W1r, const float* __restrict__ W2l,
    float* __restrict__ sval, int N)
{
    int i = blockIdx.x * blockDim.x + threadIdx.x;
    if (i >= N) return;
    float inv = 1.0f / fmaxf(deg[i], 1.0f);
    float2 a = *reinterpret_cast<const float2*>(agg1 + 2 * (size_t)i);
    float m0 = a.x * inv, m1 = a.y * inv;
    float2 xv = *reinterpret_cast<const float2*>(x + 2 * (size_t)i);
    float s = 0.0f;
#pragma unroll
    for (int o = 0; o < 16; ++o) {
        float h = m0 * W1l[2 * o] + m1 * W1l[2 * o + 1] + b1[o]
                + xv.x * W1r[2 * o] + xv.y * W1r[2 * o + 1];
        s += fmaxf(h, 0.0f) * W2l[o];
    }
    sval[i] = s;
}
__global__ __launch_bounds__(256) void k_scatter2_fb(
    const int* __restrict__ src, const int* __restrict__ dst,
    const float* __restrict__ sval, float* __restrict__ agg_s, int E)
{
    int stride = gridDim.x * blockDim.x;
    for (int e = blockIdx.x * blockDim.x + threadIdx.x; e < E; e += stride)
        unsafeAtomicAdd(&agg_s[dst[e]], sval[src[e]]);
}
__global__ __launch_bounds__(256) void k_node2_fb(
    const float* __restrict__ x, const float* __restrict__ agg1, const float* __restrict__ deg,
    const float* __restrict__ agg_s,
    const float* __restrict__ W1l, const float* __restrict__ b1,
    const float* __restrict__ W1r, const float* __restrict__ W2r, const float* __restrict__ b2,
    float* __restrict__ out, int N)
{
    int i = blockIdx.x * blockDim.x + threadIdx.x;
    if (i >= N) return;
    float inv = 1.0f / fmaxf(deg[i], 1.0f);
    float2 a = *reinterpret_cast<const float2*>(agg1 + 2 * (size_t)i);
    float m0 = a.x * inv, m1 = a.y * inv;
    float2 xv = *reinterpret_cast<const float2*>(x + 2 * (size_t)i);
    float t = agg_s[i] * inv + b2[0];
#pragma unroll
    for (int o = 0; o < 16; ++o) {
        float h = m0 * W1l[2 * o] + m1 * W1l[2 * o + 1] + b1[o]
                + xv.x * W1r[2 * o] + xv.y * W1r[2 * o + 1];
        t += fmaxf(h, 0.0f) * W2r[o];
    }
    out[i] = 1.0f / (1.0f + expf(-t));
}

extern "C" void kernel_launch(void* const* d_in, const int* in_sizes, int n_in,
                              void* d_out, int out_size, void* d_ws, size_t ws_size,
                              hipStream_t stream) {
    const float* x   = (const float*)d_in[0];
    const int*   ei  = (const int*)d_in[1];
    const float* W1l = (const float*)d_in[2];
    const float* b1  = (const float*)d_in[3];
    const float* W1r = (const float*)d_in[4];
    const float* W2l = (const float*)d_in[5];
    const float* b2  = (const float*)d_in[6];
    const float* W2r = (const float*)d_in[7];

    const int N = in_sizes[0] / 2;
    const int E = in_sizes[1] / 2;
    const int* src = ei;
    const int* dst = ei + (size_t)E;
    float* out = (float*)d_out;

    const int NB = (N + BUCKET_NODES - 1) >> BUCKET_BITS;
    const int chunk = (E + PGRID - 1) / PGRID;

    // ws: cursor[512*16] | entries[NB*CAP] | sq[N] | t0a[N] | inva[N] | dega[N]
    size_t needed = 512 * CSTRIDE * 4 + (size_t)NB * CAP * 4 + 4 * (size_t)N * 4;
    if (NB <= 512 && chunk <= MAXCHUNK && ws_size >= needed) {
        unsigned* cursor  = (unsigned*)d_ws;
        unsigned* entries = cursor + 512 * CSTRIDE;
        unsigned* sq      = entries + (size_t)NB * CAP;
        float*    t0a     = (float*)(sq + N);
        float*    inva    = t0a + N;
        unsigned* dega    = (unsigned*)(inva + N);

        k_init<<<(NB + 511) / 512, 512, 0, stream>>>(cursor, NB);
        k_part<<<PGRID, PBLOCK, 0, stream>>>(src, dst, cursor, entries, E, NB);
        k_agg1<<<NB, ABLOCK, 0, stream>>>(entries, cursor, x, W1l, b1, W1r, W2l, W2r, b2,
                                          sq, t0a, inva, dega, N);
        k_agg2<<<NB, ABLOCK, 0, stream>>>(entries, cursor, sq, t0a, inva, dega, out, N);
    } else {
        float* agg1  = (float*)d_ws;
        float* deg   = agg1 + 2 * (size_t)N;
        float* agg_s = deg + (size_t)N;
        float* sval  = agg_s + (size_t)N;
        hipMemsetAsync(d_ws, 0, 4 * (size_t)N * sizeof(float), stream);
        const int eblocks = 2048, nblocks = (N + 255) / 256;
        k_scatter1_fb<<<eblocks, 256, 0, stream>>>(src, dst, x, agg1, deg, E);
        k_node1_fb<<<nblocks, 256, 0, stream>>>(x, agg1, deg, W1l, b1, W1r, W2l, sval, N);
        k_scatter2_fb<<<eblocks, 256, 0, stream>>>(src, dst, sval, agg_s, E);
        k_node2_fb<<<nblocks, 256, 0, stream>>>(x, agg1, deg, agg_s, W1l, b1, W1r, W2r, b2, out, N);
    }
}